// Round 5
// baseline (451.690 us; speedup 1.0000x reference)
//
#include <hip/hip_runtime.h>
#include <math.h>

// Problem constants (fixed by setup_inputs)
constexpr int KV_LEN    = 4096;
constexpr int PAGE_SZ   = 16;
constexpr int SHIFT     = 16;
constexpr int BSZ       = 4;
constexpr int SEQ_LEN   = 512;
constexpr int HEADS     = 16;
constexpr int HEAD_DIM  = 128;
constexpr int PAGES     = BSZ * KV_LEN / PAGE_SZ;  // 1024
constexpr int PPS       = PAGES / BSZ;             // 256 pages per sequence
constexpr int KEEP      = KV_LEN - SHIFT;          // 4080
constexpr int CUT       = KEEP - SEQ_LEN;          // 3568 = 223*16
constexpr int PAGE_STR  = 2 * PAGE_SZ * HEADS * HEAD_DIM;  // 65536 floats
constexpr int C_STR     = PAGE_SZ * HEADS * HEAD_DIM;      // 32768
constexpr int S_STR     = HEADS * HEAD_DIM;                // 2048

// Key alignment facts exploited below (all exact, compile-time):
//   SHIFT+SEQ_LEN = 528 = 33*PAGE_SZ  -> shifted-window source is page pp+33, same slab s
//   CUT  = 223*PAGE_SZ, KEEP = 255*PAGE_SZ -> region branch is s-invariant per page
// So each (page, c) output half is ONE contiguous 128 KB copy (+ RoPE on k).

typedef float f32x4 __attribute__((ext_vector_type(4)));

// inv[page] = position of `page` in kv_page_indices, or -1 if absent.
// PAGES==1024 fits one block; __syncthreads orders init vs scatter.
__global__ void build_inv(const int* __restrict__ idx, int* __restrict__ inv, int n) {
    int t = threadIdx.x;
    if (t < n) inv[t] = -1;
    __syncthreads();
    if (t < n) inv[idx[t]] = t;
}

// One block per (page, c): 256 threads stream a contiguous 128 KB half-page.
// Thread owns the RoPE pair (off1, off1+64) and loops over the 16 slabs with
// constant stride S_STR: 2 NT loads + 2 NT stores per iter, unroll 4.
// Trig math is element-for-element identical to previous versions
// (exp2f(lane*c), sincosf(j*invf), shfl distribute) -> absmax unchanged.
__global__ __launch_bounds__(256) void kv_shift_rope(
    const float* __restrict__ kin, const float* __restrict__ vin,
    const float* __restrict__ dc,  const int*  __restrict__ pidx,
    const int*  __restrict__ inv,  float* __restrict__ out)
{
    int blk = blockIdx.x;          // PAGES*2 = 2048
    int p   = blk >> 1;
    int c   = blk & 1;             // 0=k, 1=v

    int tid = threadIdx.x;
    int h   = tid >> 4;
    int d0  = (tid & 15) << 2;     // 0..60 step 4
    int off1 = h * HEAD_DIM + d0;
    int off2 = off1 + 64;

    float* op = out + (size_t)p * PAGE_STR + c * C_STR;

    int pos = inv[p];              // block-uniform
    const float* sp;
    bool rope = false;
    int  j0   = 0;
    if (pos < 0) {
        // page not updated: passthrough copy of the same half-page
        sp = dc + (size_t)p * PAGE_STR + c * C_STR;
    } else {
        int b  = pos >> 8;         // /PPS
        int pp = pos & (PPS - 1);
        j0   = pp * PAGE_SZ;       // first sequence position of this page
        rope = (c == 0);
        if (pp >= CUT / PAGE_SZ && pp < KEEP / PAGE_SZ) {
            // new tokens: 16 contiguous rows of kin/vin
            const float* base = c ? vin : kin;
            sp = base + (size_t)(b * SEQ_LEN + (j0 - CUT)) * S_STR;
        } else {
            // shifted window (pp<=222 -> page pp+33) or retained tail (pp==255)
            int q = (pp < CUT / PAGE_SZ) ? (pp + (SHIFT + SEQ_LEN) / PAGE_SZ) : pp;
            int srcpage = pidx[b * PPS + q];
            sp = dc + (size_t)srcpage * PAGE_STR + c * C_STR;
        }
    }

    if (rope) {
        // RoPE (neox rotate-half), fp32. Lane L holds sincos for freq index L.
        const float neg_log2_theta_over_half = -0.20762050593046939f; // -log2(10000)/64
        int   lane = tid & 63;
        float invf = exp2f((float)lane * neg_log2_theta_over_half);
        #pragma unroll 4
        for (int s = 0; s < PAGE_SZ; ++s) {
            const float* spс = sp + s * S_STR;
            f32x4 x1 = __builtin_nontemporal_load((const f32x4*)(spс + off1));
            f32x4 x2 = __builtin_nontemporal_load((const f32x4*)(spс + off2));

            float sn_l, cs_l;
            sincosf((float)(j0 + s) * invf, &sn_l, &cs_l);
            float cs[4], sn[4];
            #pragma unroll
            for (int i = 0; i < 4; i++) {
                cs[i] = __shfl(cs_l, d0 + i);
                sn[i] = __shfl(sn_l, d0 + i);
            }
            f32x4 o1, o2;
            #pragma unroll
            for (int i = 0; i < 4; i++) {
                o1[i] = x1[i] * cs[i] - x2[i] * sn[i];
                o2[i] = x1[i] * sn[i] + x2[i] * cs[i];
            }
            float* opс = op + s * S_STR;
            __builtin_nontemporal_store(o1, (f32x4*)(opс + off1));
            __builtin_nontemporal_store(o2, (f32x4*)(opс + off2));
        }
    } else {
        #pragma unroll 4
        for (int s = 0; s < PAGE_SZ; ++s) {
            const float* spс = sp + s * S_STR;
            float* opс = op + s * S_STR;
            f32x4 x1 = __builtin_nontemporal_load((const f32x4*)(spс + off1));
            f32x4 x2 = __builtin_nontemporal_load((const f32x4*)(spс + off2));
            __builtin_nontemporal_store(x1, (f32x4*)(opс + off1));
            __builtin_nontemporal_store(x2, (f32x4*)(opс + off2));
        }
    }
}

extern "C" void kernel_launch(void* const* d_in, const int* in_sizes, int n_in,
                              void* d_out, int out_size, void* d_ws, size_t ws_size,
                              hipStream_t stream) {
    const float* kin  = (const float*)d_in[0];
    const float* vin  = (const float*)d_in[1];
    const float* dc   = (const float*)d_in[2];
    const int*   pidx = (const int*)d_in[3];
    int pages = in_sizes[3];           // 1024

    int* inv = (int*)d_ws;             // 4 KB scratch
    build_inv<<<1, pages, 0, stream>>>(pidx, inv, pages);

    int grid = PAGES * 2;              // 2048 blocks: one per (page, c)
    kv_shift_rope<<<grid, 256, 0, stream>>>(kin, vin, dc, pidx, inv, (float*)d_out);
}

// Round 9
// 440.085 us; speedup vs baseline: 1.0264x; 1.0264x over previous
//
#include <hip/hip_runtime.h>
#include <math.h>

// Problem constants (fixed by setup_inputs)
constexpr int KV_LEN    = 4096;
constexpr int PAGE_SZ   = 16;
constexpr int SHIFT     = 16;
constexpr int BSZ       = 4;
constexpr int SEQ_LEN   = 512;
constexpr int HEADS     = 16;
constexpr int HEAD_DIM  = 128;
constexpr int PAGES     = BSZ * KV_LEN / PAGE_SZ;  // 1024
constexpr int PPS       = PAGES / BSZ;             // 256 pages per sequence
constexpr int KEEP      = KV_LEN - SHIFT;          // 4080
constexpr int CUT       = KEEP - SEQ_LEN;          // 3568: j<CUT -> cache[j+528]
constexpr int PAGE_STR  = 2 * PAGE_SZ * HEADS * HEAD_DIM;  // 65536 floats
constexpr int C_STR     = PAGE_SZ * HEADS * HEAD_DIM;      // 32768
constexpr int S_STR     = HEADS * HEAD_DIM;                // 2048

typedef float f32x4 __attribute__((ext_vector_type(4)));

// inv[page] = position of `page` in kv_page_indices, or -1 if absent.
// PAGES==1024 fits one block; __syncthreads orders init vs scatter.
__global__ void build_inv(const int* __restrict__ idx, int* __restrict__ inv, int n) {
    int t = threadIdx.x;
    if (t < n) inv[t] = -1;
    __syncthreads();
    if (t < n) inv[idx[t]] = t;
}

// One block per (page, c, s) slab: 16 heads x 128 dims = 2048 floats.
// 256 threads, each handles the RoPE pair (d0..d0+3, d0+64..d0+67) as 2x float4.
// Trig: ONE sincos per lane (freq = lane index), distributed via __shfl —
// bitwise-identical to the per-thread 4x sincosf it replaces, at 1/4 the VALU.
// All bulk traffic is read-once/write-once streaming -> nontemporal.
// (Exact revert to the best-measured R1 source, 441.1 µs: the position-indexed
// scatter structure failed container acquisition 3x in a row; this structure
// is 3-for-3 clean.)
__global__ __launch_bounds__(256) void kv_shift_rope(
    const float* __restrict__ kin, const float* __restrict__ vin,
    const float* __restrict__ dc,  const int*  __restrict__ pidx,
    const int*  __restrict__ inv,  float* __restrict__ out)
{
    int blk = blockIdx.x;          // PAGES*2*PAGE_SZ
    int p   = blk >> 5;
    int rem = blk & 31;
    int c   = rem >> 4;            // 0=k, 1=v
    int s   = rem & 15;

    int tid = threadIdx.x;
    int h   = tid >> 4;
    int d0  = (tid & 15) << 2;     // 0..60 step 4

    float* op   = out + (size_t)p * PAGE_STR + c * C_STR + s * S_STR;
    int    off1 = h * HEAD_DIM + d0;
    int    off2 = off1 + 64;

    int pos = inv[p];              // block-uniform
    const float* sp;
    int j = 0;
    if (pos < 0) {
        // page not updated: passthrough copy
        sp = dc + (size_t)p * PAGE_STR + c * C_STR + s * S_STR;
    } else {
        int b  = pos >> 8;         // /PPS (256)
        int pp = pos & (PPS - 1);
        j = pp * PAGE_SZ + s;      // absolute sequence position, 0..4095
        if (j >= CUT && j < KEEP) {
            // sourced from the new k/v tensors
            const float* base = (c == 0) ? kin : vin;
            sp = base + (size_t)(b * SEQ_LEN + (j - CUT)) * S_STR;
        } else {
            // sourced from the old cache (shifted window or retained tail)
            int t2 = (j < CUT) ? (j + SHIFT + SEQ_LEN) : j;
            int q  = t2 >> 4;
            int ss = t2 & 15;
            int srcpage = pidx[b * PPS + q];
            sp = dc + (size_t)srcpage * PAGE_STR + c * C_STR + ss * S_STR;
        }
    }

    // Issue the long-pole loads first; trig below executes under their latency.
    f32x4 x1 = __builtin_nontemporal_load((const f32x4*)(sp + off1));
    f32x4 x2 = __builtin_nontemporal_load((const f32x4*)(sp + off2));

    if (pos >= 0 && c == 0) {
        // RoPE (neox rotate-half) at position j, fp32.
        // Lane L computes sincos for frequency index L; shfl distributes.
        const float neg_log2_theta_over_half = -0.20762050593046939f; // -log2(10000)/64
        int   lane  = tid & 63;
        float invf  = exp2f((float)lane * neg_log2_theta_over_half);
        float sn_l, cs_l;
        sincosf((float)j * invf, &sn_l, &cs_l);

        float cs[4], sn[4];
        #pragma unroll
        for (int i = 0; i < 4; i++) {
            cs[i] = __shfl(cs_l, d0 + i);
            sn[i] = __shfl(sn_l, d0 + i);
        }

        f32x4 o1, o2;
        #pragma unroll
        for (int i = 0; i < 4; i++) {
            o1[i] = x1[i] * cs[i] - x2[i] * sn[i];
            o2[i] = x1[i] * sn[i] + x2[i] * cs[i];
        }
        __builtin_nontemporal_store(o1, (f32x4*)(op + off1));
        __builtin_nontemporal_store(o2, (f32x4*)(op + off2));
    } else {
        __builtin_nontemporal_store(x1, (f32x4*)(op + off1));
        __builtin_nontemporal_store(x2, (f32x4*)(op + off2));
    }
}

extern "C" void kernel_launch(void* const* d_in, const int* in_sizes, int n_in,
                              void* d_out, int out_size, void* d_ws, size_t ws_size,
                              hipStream_t stream) {
    const float* kin  = (const float*)d_in[0];
    const float* vin  = (const float*)d_in[1];
    const float* dc   = (const float*)d_in[2];
    const int*   pidx = (const int*)d_in[3];
    int pages = in_sizes[3];           // 1024

    int* inv = (int*)d_ws;             // 4 KB scratch
    build_inv<<<1, pages, 0, stream>>>(pidx, inv, pages);

    int grid = PAGES * 2 * PAGE_SZ;    // 32768 blocks
    kv_shift_rope<<<grid, 256, 0, stream>>>(kin, vin, dc, pidx, inv, (float*)d_out);
}